// Round 14
// baseline (2803.405 us; speedup 1.0000x reference)
//
#include <hip/hip_runtime.h>
#include <hip/hip_bf16.h>

// R14: R10 kernel (best, 192.1us) verbatim + 4 pure-read granularity diags
// (6 passes over x each -> >700us, guaranteed top-5 over ~490us fills):
//   diag_a_128B : R10 pattern, 128B-complete lines @ 3KB stride
//   diag_b_256B : 256B chunks @ 3KB stride (BK=64 analog)
//   diag_c_512B : 512B chunks @ 3KB stride (BK=128 analog)
//   diag_d_seq  : per-wave sequential rows (96KB contiguous per wave)
#define DIM    768
#define NC     53
#define NCP    64
#define MTB    256
#define NTH    512
#define KSTEP  32
#define NSTEPS 24
#define APAD   40
#define D4v    192      // DIM/4
#define DREP   6

typedef __attribute__((ext_vector_type(8))) short short8;
typedef __attribute__((ext_vector_type(4))) float f32x4;

static __device__ inline unsigned short f2bf(float f) {
    unsigned u = __float_as_uint(f);
    u += 0x7fff + ((u >> 16) & 1);           // RNE
    return (unsigned short)(u >> 16);
}

__global__ void wconv_kernel(const float* __restrict__ W, unsigned short* __restrict__ Wt) {
    const int idx = blockIdx.x * 256 + threadIdx.x;
    if (idx >= NCP * DIM) return;
    const int c = idx / DIM, k = idx - c * DIM;
    Wt[idx] = f2bf((c < NC) ? W[c * DIM + k] : 0.f);
}

static __device__ inline void cvt_store8(unsigned short* dst, const float4 v) {
    union { __hip_bfloat162 h[2]; uint2 u; } z;
    z.h[0] = __float22bfloat162_rn(make_float2(v.x, v.y));
    z.h[1] = __float22bfloat162_rn(make_float2(v.z, v.w));
    *reinterpret_cast<uint2*>(dst) = z.u;
}

__global__ __launch_bounds__(NTH) void bag_attn_mfma4(
    const float* __restrict__ x,
    const unsigned short* __restrict__ Wt,
    const float* __restrict__ bias,
    const int*   __restrict__ query,
    float*       __restrict__ out)
{
    __shared__ __align__(16) unsigned short Ab[2][MTB * APAD];
    __shared__ float att_sm[16][16];
    __shared__ int   qbuf[MTB];

    const int t   = threadIdx.x;
    const int w   = t >> 6;
    const int l   = t & 63;
    const int blk = blockIdx.x;
    const int row_g = blk * MTB;

    if (t < MTB) qbuf[t] = query[row_g + t];

    const float4* xp = reinterpret_cast<const float4*>(x)
                     + (size_t)(row_g + 32 * w + (l >> 3)) * D4v + (l & 7);
    unsigned short* d0[4];
    unsigned short* d1[4];
    #pragma unroll
    for (int i = 0; i < 4; ++i) {
        const int off = (32 * w + 8 * i + (l >> 3)) * APAD + (l & 7) * 4;
        d0[i] = &Ab[0][off];
        d1[i] = &Ab[1][off];
    }

    f32x4 acc[2][4];
    #pragma unroll
    for (int mi = 0; mi < 2; ++mi)
        #pragma unroll
        for (int ni = 0; ni < 4; ++ni)
            acc[mi][ni] = (f32x4){0.f, 0.f, 0.f, 0.f};

    float4 rA[4], rB[4];
    #pragma unroll
    for (int i = 0; i < 4; ++i) rA[i] = xp[i * 8 * D4v + 0 * 8];
    #pragma unroll
    for (int i = 0; i < 4; ++i) rB[i] = xp[i * 8 * D4v + 1 * 8];
    #pragma unroll
    for (int i = 0; i < 4; ++i) cvt_store8(d0[i], rA[i]);
    __syncthreads();

#define COMPUTE(p, kk)                                                         \
    {                                                                          \
        short8 bfr[4];                                                         \
        _Pragma("unroll")                                                      \
        for (int ni = 0; ni < 4; ++ni)                                         \
            bfr[ni] = *reinterpret_cast<const short8*>(                        \
                Wt + ((16 * ni + (l & 15)) * DIM + (kk) * KSTEP + (l >> 4) * 8)); \
        short8 afr[2];                                                         \
        _Pragma("unroll")                                                      \
        for (int mi = 0; mi < 2; ++mi)                                         \
            afr[mi] = *reinterpret_cast<const short8*>(                        \
                &Ab[p][(32 * w + 16 * mi + (l & 15)) * APAD + (l >> 4) * 8]);  \
        _Pragma("unroll")                                                      \
        for (int mi = 0; mi < 2; ++mi)                                         \
            _Pragma("unroll")                                                  \
            for (int ni = 0; ni < 4; ++ni)                                     \
                acc[mi][ni] = __builtin_amdgcn_mfma_f32_16x16x32_bf16(         \
                    afr[mi], bfr[ni], acc[mi][ni], 0, 0, 0);                   \
    }

    for (int kk = 0; kk < NSTEPS; kk += 2) {
        if (kk + 2 < NSTEPS) {
            #pragma unroll
            for (int i = 0; i < 4; ++i)
                rA[i] = xp[i * 8 * D4v + (kk + 2) * 8];
        }
        COMPUTE(0, kk);
        #pragma unroll
        for (int i = 0; i < 4; ++i) cvt_store8(d1[i], rB[i]);
        __syncthreads();
        if (kk + 3 < NSTEPS) {
            #pragma unroll
            for (int i = 0; i < 4; ++i)
                rB[i] = xp[i * 8 * D4v + (kk + 3) * 8];
        }
        COMPUTE(1, kk + 1);
        if (kk + 2 < NSTEPS) {
            #pragma unroll
            for (int i = 0; i < 4; ++i) cvt_store8(d0[i], rA[i]);
            __syncthreads();
        }
    }
#undef COMPUTE

    #pragma unroll
    for (int mi = 0; mi < 2; ++mi) {
        #pragma unroll
        for (int r = 0; r < 4; ++r) {
            const int s_loc = ((l >> 4) << 2) + r;
            const int q = qbuf[32 * w + 16 * mi + s_loc];
            if ((q & 15) == (l & 15)) {
                float v = acc[mi][0][r];
                if ((q >> 4) == 1) v = acc[mi][1][r];
                if ((q >> 4) == 2) v = acc[mi][2][r];
                if ((q >> 4) == 3) v = acc[mi][3][r];
                att_sm[2 * w + mi][s_loc] = v;
            }
        }
    }

    #pragma unroll
    for (int mi = 0; mi < 2; ++mi) {
        const int bag = 2 * w + mi;
        const float4* a4 = reinterpret_cast<const float4*>(&att_sm[bag][0]);
        const float4 A0 = a4[0], A1 = a4[1], A2 = a4[2], A3 = a4[3];
        float mx = fmaxf(fmaxf(fmaxf(A0.x, A0.y), fmaxf(A0.z, A0.w)),
                  fmaxf(fmaxf(fmaxf(A1.x, A1.y), fmaxf(A1.z, A1.w)),
                  fmaxf(fmaxf(fmaxf(A2.x, A2.y), fmaxf(A2.z, A2.w)),
                        fmaxf(fmaxf(A3.x, A3.y), fmaxf(A3.z, A3.w)))));
        float zz = __expf(A0.x-mx)+__expf(A0.y-mx)+__expf(A0.z-mx)+__expf(A0.w-mx)
                 + __expf(A1.x-mx)+__expf(A1.y-mx)+__expf(A1.z-mx)+__expf(A1.w-mx)
                 + __expf(A2.x-mx)+__expf(A2.y-mx)+__expf(A2.z-mx)+__expf(A2.w-mx)
                 + __expf(A3.x-mx)+__expf(A3.y-mx)+__expf(A3.z-mx)+__expf(A3.w-mx);
        const float inv = 1.f / zz;
        const int grp = l >> 4;
        float4 As = A0;
        if (grp == 1) As = A1;
        if (grp == 2) As = A2;
        if (grp == 3) As = A3;
        const float w0 = __expf(As.x - mx) * inv;
        const float w1 = __expf(As.y - mx) * inv;
        const float w2 = __expf(As.z - mx) * inv;
        const float w3 = __expf(As.w - mx) * inv;
        #pragma unroll
        for (int ni = 0; ni < 4; ++ni) {
            float p = w0 * acc[mi][ni][0] + w1 * acc[mi][ni][1]
                    + w2 * acc[mi][ni][2] + w3 * acc[mi][ni][3];
            p += __shfl_xor(p, 16, 64);
            p += __shfl_xor(p, 32, 64);
            if (l < 16) {
                const int c = 16 * ni + l;
                if (c < NC)
                    out[(size_t)(blk * 16 + bag) * NC + c] = p + bias[c];
            }
        }
    }
}

// ---- granularity diags: grid 1024x512, block reads rows [256b,256b+256) ----
__global__ __launch_bounds__(NTH) void diag_a_128B(
    const float* __restrict__ x, float* __restrict__ ws)
{
    const int t = threadIdx.x, w = t >> 6, l = t & 63;
    const float4* xp = reinterpret_cast<const float4*>(x)
        + (size_t)(blockIdx.x * MTB + 32 * w + (l >> 3)) * D4v + (l & 7);
    float4 s = {0,0,0,0};
    for (int rep = 0; rep < DREP; ++rep)
        for (int k = 0; k < 24; ++k) {
            #pragma unroll
            for (int i = 0; i < 4; ++i) {
                const float4 v = xp[(size_t)i * 8 * D4v + k * 8];
                s.x += v.x; s.y += v.y; s.z += v.z; s.w += v.w;
            }
        }
    ws[(size_t)blockIdx.x * NTH + t] = s.x + s.y + s.z + s.w;
}

__global__ __launch_bounds__(NTH) void diag_b_256B(
    const float* __restrict__ x, float* __restrict__ ws)
{
    const int t = threadIdx.x, w = t >> 6, l = t & 63;
    const float4* xp = reinterpret_cast<const float4*>(x)
        + (size_t)(blockIdx.x * MTB + 32 * w + (l >> 4)) * D4v + (l & 15);
    float4 s = {0,0,0,0};
    for (int rep = 0; rep < DREP; ++rep)
        for (int k = 0; k < 12; ++k) {
            #pragma unroll
            for (int i = 0; i < 8; ++i) {
                const float4 v = xp[(size_t)i * 4 * D4v + k * 16];
                s.x += v.x; s.y += v.y; s.z += v.z; s.w += v.w;
            }
        }
    ws[(size_t)blockIdx.x * NTH + t] = s.x + s.y + s.z + s.w;
}

__global__ __launch_bounds__(NTH) void diag_c_512B(
    const float* __restrict__ x, float* __restrict__ ws)
{
    const int t = threadIdx.x, w = t >> 6, l = t & 63;
    const float4* xp = reinterpret_cast<const float4*>(x)
        + (size_t)(blockIdx.x * MTB + 32 * w + (l >> 5)) * D4v + (l & 31);
    float4 s = {0,0,0,0};
    for (int rep = 0; rep < DREP; ++rep)
        for (int k = 0; k < 6; ++k) {
            #pragma unroll
            for (int i = 0; i < 16; ++i) {
                const float4 v = xp[(size_t)i * 2 * D4v + k * 32];
                s.x += v.x; s.y += v.y; s.z += v.z; s.w += v.w;
            }
        }
    ws[(size_t)blockIdx.x * NTH + t] = s.x + s.y + s.z + s.w;
}

__global__ __launch_bounds__(NTH) void diag_d_seq(
    const float* __restrict__ x, float* __restrict__ ws)
{
    const int t = threadIdx.x, w = t >> 6, l = t & 63;
    // wave reads its 32-row panel (96KB) fully sequentially, 1KB per instr
    const float4* xp = reinterpret_cast<const float4*>(x)
        + (size_t)(blockIdx.x * MTB + 32 * w) * D4v + l;
    float4 s = {0,0,0,0};
    for (int rep = 0; rep < DREP; ++rep)
        for (int j = 0; j < 96; j += 8) {
            #pragma unroll
            for (int i = 0; i < 8; ++i) {
                const float4 v = xp[(size_t)(j + i) * 64];
                s.x += v.x; s.y += v.y; s.z += v.z; s.w += v.w;
            }
        }
    ws[(size_t)blockIdx.x * NTH + t] = s.x + s.y + s.z + s.w;
}

extern "C" void kernel_launch(void* const* d_in, const int* in_sizes, int n_in,
                              void* d_out, int out_size, void* d_ws, size_t ws_size,
                              hipStream_t stream) {
    const float* x     = (const float*)d_in[0];
    const float* W     = (const float*)d_in[1];
    const float* bias  = (const float*)d_in[2];
    const int*   query = (const int*)d_in[4];
    float* out = (float*)d_out;

    unsigned short* Wt = (unsigned short*)d_ws;           // 96 KiB
    float* diag = (float*)((char*)d_ws + (1 << 20));

    const int nrows = in_sizes[0] / DIM;                  // 262144
    const int nblk  = nrows / MTB;                        // 1024

    wconv_kernel<<<(NCP * DIM + 255) / 256, 256, 0, stream>>>(W, Wt);
    bag_attn_mfma4<<<nblk, NTH, 0, stream>>>(x, Wt, bias, query, out);

    diag_a_128B<<<nblk, NTH, 0, stream>>>(x, diag + 0 * nblk * NTH);
    diag_b_256B<<<nblk, NTH, 0, stream>>>(x, diag + 1 * nblk * NTH);
    diag_c_512B<<<nblk, NTH, 0, stream>>>(x, diag + 2 * nblk * NTH);
    diag_d_seq <<<nblk, NTH, 0, stream>>>(x, diag + 3 * nblk * NTH);
}

// Round 15
// 946.303 us; speedup vs baseline: 2.9625x; 2.9625x over previous
//
#include <hip/hip_runtime.h>
#include <hip/hip_bf16.h>

// R15: main = R10 + B-through-LDS (B k-slice double-buffered in LDS, staged
// once per block phase; kills the 786MB global B re-read stream).
// Plus 2 ablation kernels (x5 reps, results -> d_ws) to pin R10's +80us:
//   abl_stage : R10 staging schedule only (loads+cvt+ds_write+barriers)
//   abl_noB   : R10 with MFMA fed from A-frags (zero B loads)
#define DIM    768
#define NC     53
#define NCP    64
#define MTB    256
#define NTH    512
#define KSTEP  32
#define NSTEPS 24
#define APAD   40
#define D4v    192
#define NABL   5

typedef __attribute__((ext_vector_type(8))) short short8;
typedef __attribute__((ext_vector_type(4))) float f32x4;

static __device__ inline unsigned short f2bf(float f) {
    unsigned u = __float_as_uint(f);
    u += 0x7fff + ((u >> 16) & 1);           // RNE
    return (unsigned short)(u >> 16);
}

__global__ void wconv_kernel(const float* __restrict__ W, unsigned short* __restrict__ Wt) {
    const int idx = blockIdx.x * 256 + threadIdx.x;
    if (idx >= NCP * DIM) return;
    const int c = idx / DIM, k = idx - c * DIM;
    Wt[idx] = f2bf((c < NC) ? W[c * DIM + k] : 0.f);
}

static __device__ inline void cvt_store8(unsigned short* dst, const float4 v) {
    union { __hip_bfloat162 h[2]; uint2 u; } z;
    z.h[0] = __float22bfloat162_rn(make_float2(v.x, v.y));
    z.h[1] = __float22bfloat162_rn(make_float2(v.z, v.w));
    *reinterpret_cast<uint2*>(dst) = z.u;
}

// ---------------- main kernel: R10 + B via LDS ----------------
__global__ __launch_bounds__(NTH) void bag_attn_blds(
    const float* __restrict__ x,              // [N][768] fp32
    const unsigned short* __restrict__ Wt,    // [64][768] bf16 (d_ws)
    const float* __restrict__ bias,           // [53]
    const int*   __restrict__ query,          // [N]
    float*       __restrict__ out)            // [B][53]
{
    __shared__ __align__(16) unsigned short Ab[2][MTB * APAD];   // 40 KiB
    __shared__ __align__(16) unsigned short Bsm[2][64 * APAD];   // 10 KiB
    __shared__ float att_sm[16][16];
    __shared__ int   qbuf[MTB];

    const int t   = threadIdx.x;
    const int w   = t >> 6;
    const int l   = t & 63;
    const int blk = blockIdx.x;
    const int row_g = blk * MTB;

    if (t < MTB) qbuf[t] = query[row_g + t];

    // A staging (cache-line-complete, wave-private rows 32w..32w+31)
    const float4* xp = reinterpret_cast<const float4*>(x)
                     + (size_t)(row_g + 32 * w + (l >> 3)) * D4v + (l & 7);
    unsigned short* d0[4];
    unsigned short* d1[4];
    #pragma unroll
    for (int i = 0; i < 4; ++i) {
        const int off = (32 * w + 8 * i + (l >> 3)) * APAD + (l & 7) * 4;
        d0[i] = &Ab[0][off];
        d1[i] = &Ab[1][off];
    }

    // B staging: thread t -> row t>>3 (0..63), 8B at elem (t&7)*4 of k-slice
    const int brow = t >> 3, bcol = (t & 7) * 4;
    const unsigned short* bsrc = Wt + brow * DIM + bcol;
    const int bofs = brow * APAD + bcol;

    f32x4 acc[2][4];
    #pragma unroll
    for (int mi = 0; mi < 2; ++mi)
        #pragma unroll
        for (int ni = 0; ni < 4; ++ni)
            acc[mi][ni] = (f32x4){0.f, 0.f, 0.f, 0.f};

    float4 rA[4], rB[4];
    uint2  bA, bB;
    #pragma unroll
    for (int i = 0; i < 4; ++i) rA[i] = xp[i * 8 * D4v + 0 * 8];
    #pragma unroll
    for (int i = 0; i < 4; ++i) rB[i] = xp[i * 8 * D4v + 1 * 8];
    bA = *reinterpret_cast<const uint2*>(bsrc);
    bB = *reinterpret_cast<const uint2*>(bsrc + KSTEP);
    #pragma unroll
    for (int i = 0; i < 4; ++i) cvt_store8(d0[i], rA[i]);
    *reinterpret_cast<uint2*>(&Bsm[0][bofs]) = bA;
    __syncthreads();

#define COMPUTE(p)                                                             \
    {                                                                          \
        short8 bfr[4];                                                         \
        _Pragma("unroll")                                                      \
        for (int ni = 0; ni < 4; ++ni)                                         \
            bfr[ni] = *reinterpret_cast<const short8*>(                        \
                &Bsm[p][(16 * ni + (l & 15)) * APAD + (l >> 4) * 8]);          \
        short8 afr[2];                                                         \
        _Pragma("unroll")                                                      \
        for (int mi = 0; mi < 2; ++mi)                                         \
            afr[mi] = *reinterpret_cast<const short8*>(                        \
                &Ab[p][(32 * w + 16 * mi + (l & 15)) * APAD + (l >> 4) * 8]);  \
        _Pragma("unroll")                                                      \
        for (int mi = 0; mi < 2; ++mi)                                         \
            _Pragma("unroll")                                                  \
            for (int ni = 0; ni < 4; ++ni)                                     \
                acc[mi][ni] = __builtin_amdgcn_mfma_f32_16x16x32_bf16(         \
                    afr[mi], bfr[ni], acc[mi][ni], 0, 0, 0);                   \
    }

    for (int kk = 0; kk < NSTEPS; kk += 2) {
        if (kk + 2 < NSTEPS) {
            #pragma unroll
            for (int i = 0; i < 4; ++i) rA[i] = xp[i * 8 * D4v + (kk + 2) * 8];
            bA = *reinterpret_cast<const uint2*>(bsrc + (kk + 2) * KSTEP);
        }
        COMPUTE(0);
        #pragma unroll
        for (int i = 0; i < 4; ++i) cvt_store8(d1[i], rB[i]);
        *reinterpret_cast<uint2*>(&Bsm[1][bofs]) = bB;
        __syncthreads();
        if (kk + 3 < NSTEPS) {
            #pragma unroll
            for (int i = 0; i < 4; ++i) rB[i] = xp[i * 8 * D4v + (kk + 3) * 8];
            bB = *reinterpret_cast<const uint2*>(bsrc + (kk + 3) * KSTEP);
        }
        COMPUTE(1);
        if (kk + 2 < NSTEPS) {
            #pragma unroll
            for (int i = 0; i < 4; ++i) cvt_store8(d0[i], rA[i]);
            *reinterpret_cast<uint2*>(&Bsm[0][bofs]) = bA;
            __syncthreads();
        }
    }
#undef COMPUTE

    // epilogue (verified): D-layout col=lane&15, row=(l>>4)*4+reg
    #pragma unroll
    for (int mi = 0; mi < 2; ++mi) {
        #pragma unroll
        for (int r = 0; r < 4; ++r) {
            const int s_loc = ((l >> 4) << 2) + r;
            const int q = qbuf[32 * w + 16 * mi + s_loc];
            if ((q & 15) == (l & 15)) {
                float v = acc[mi][0][r];
                if ((q >> 4) == 1) v = acc[mi][1][r];
                if ((q >> 4) == 2) v = acc[mi][2][r];
                if ((q >> 4) == 3) v = acc[mi][3][r];
                att_sm[2 * w + mi][s_loc] = v;
            }
        }
    }

    #pragma unroll
    for (int mi = 0; mi < 2; ++mi) {
        const int bag = 2 * w + mi;
        const float4* a4 = reinterpret_cast<const float4*>(&att_sm[bag][0]);
        const float4 A0 = a4[0], A1 = a4[1], A2 = a4[2], A3 = a4[3];
        float mx = fmaxf(fmaxf(fmaxf(A0.x, A0.y), fmaxf(A0.z, A0.w)),
                  fmaxf(fmaxf(fmaxf(A1.x, A1.y), fmaxf(A1.z, A1.w)),
                  fmaxf(fmaxf(fmaxf(A2.x, A2.y), fmaxf(A2.z, A2.w)),
                        fmaxf(fmaxf(A3.x, A3.y), fmaxf(A3.z, A3.w)))));
        float zz = __expf(A0.x-mx)+__expf(A0.y-mx)+__expf(A0.z-mx)+__expf(A0.w-mx)
                 + __expf(A1.x-mx)+__expf(A1.y-mx)+__expf(A1.z-mx)+__expf(A1.w-mx)
                 + __expf(A2.x-mx)+__expf(A2.y-mx)+__expf(A2.z-mx)+__expf(A2.w-mx)
                 + __expf(A3.x-mx)+__expf(A3.y-mx)+__expf(A3.z-mx)+__expf(A3.w-mx);
        const float inv = 1.f / zz;
        const int grp = l >> 4;
        float4 As = A0;
        if (grp == 1) As = A1;
        if (grp == 2) As = A2;
        if (grp == 3) As = A3;
        const float w0 = __expf(As.x - mx) * inv;
        const float w1 = __expf(As.y - mx) * inv;
        const float w2 = __expf(As.z - mx) * inv;
        const float w3 = __expf(As.w - mx) * inv;
        #pragma unroll
        for (int ni = 0; ni < 4; ++ni) {
            float p = w0 * acc[mi][ni][0] + w1 * acc[mi][ni][1]
                    + w2 * acc[mi][ni][2] + w3 * acc[mi][ni][3];
            p += __shfl_xor(p, 16, 64);
            p += __shfl_xor(p, 32, 64);
            if (l < 16) {
                const int c = 16 * ni + l;
                if (c < NC)
                    out[(size_t)(blk * 16 + bag) * NC + c] = p + bias[c];
            }
        }
    }
}

// ---------------- ablation 1: staging schedule only ----------------
__global__ __launch_bounds__(NTH) void abl_stage(
    const float* __restrict__ x, float* __restrict__ ws)
{
    __shared__ __align__(16) unsigned short Ab[2][MTB * APAD];
    const int t = threadIdx.x, w = t >> 6, l = t & 63;
    const float4* xp = reinterpret_cast<const float4*>(x)
        + (size_t)(blockIdx.x * MTB + 32 * w + (l >> 3)) * D4v + (l & 7);
    unsigned short* d0[4];
    unsigned short* d1[4];
    #pragma unroll
    for (int i = 0; i < 4; ++i) {
        const int off = (32 * w + 8 * i + (l >> 3)) * APAD + (l & 7) * 4;
        d0[i] = &Ab[0][off];
        d1[i] = &Ab[1][off];
    }
    float4 rA[4], rB[4];
    for (int rep = 0; rep < NABL; ++rep) {
        #pragma unroll
        for (int i = 0; i < 4; ++i) rA[i] = xp[i * 8 * D4v];
        #pragma unroll
        for (int i = 0; i < 4; ++i) rB[i] = xp[i * 8 * D4v + 8];
        #pragma unroll
        for (int i = 0; i < 4; ++i) cvt_store8(d0[i], rA[i]);
        __syncthreads();
        for (int kk = 0; kk < NSTEPS; kk += 2) {
            if (kk + 2 < NSTEPS) {
                #pragma unroll
                for (int i = 0; i < 4; ++i) rA[i] = xp[i * 8 * D4v + (kk + 2) * 8];
            }
            #pragma unroll
            for (int i = 0; i < 4; ++i) cvt_store8(d1[i], rB[i]);
            __syncthreads();
            if (kk + 3 < NSTEPS) {
                #pragma unroll
                for (int i = 0; i < 4; ++i) rB[i] = xp[i * 8 * D4v + (kk + 3) * 8];
            }
            if (kk + 2 < NSTEPS) {
                #pragma unroll
                for (int i = 0; i < 4; ++i) cvt_store8(d0[i], rA[i]);
                __syncthreads();
            }
        }
    }
    __syncthreads();
    const float s = (float)Ab[0][t] + (float)Ab[1][t]
                  + (float)Ab[0][t + NTH] + (float)Ab[1][t + NTH];
    ws[(size_t)blockIdx.x * NTH + t] = s;
}

// ---------------- ablation 2: full pipeline, zero B loads ----------------
__global__ __launch_bounds__(NTH) void abl_noB(
    const float* __restrict__ x, float* __restrict__ ws)
{
    __shared__ __align__(16) unsigned short Ab[2][MTB * APAD];
    const int t = threadIdx.x, w = t >> 6, l = t & 63;
    const float4* xp = reinterpret_cast<const float4*>(x)
        + (size_t)(blockIdx.x * MTB + 32 * w + (l >> 3)) * D4v + (l & 7);
    unsigned short* d0[4];
    unsigned short* d1[4];
    #pragma unroll
    for (int i = 0; i < 4; ++i) {
        const int off = (32 * w + 8 * i + (l >> 3)) * APAD + (l & 7) * 4;
        d0[i] = &Ab[0][off];
        d1[i] = &Ab[1][off];
    }
    f32x4 acc[2][4];
    #pragma unroll
    for (int mi = 0; mi < 2; ++mi)
        #pragma unroll
        for (int ni = 0; ni < 4; ++ni)
            acc[mi][ni] = (f32x4){0.f, 0.f, 0.f, 0.f};
    float4 rA[4], rB[4];

#define COMPUTE_NB(p)                                                          \
    {                                                                          \
        short8 afr[2];                                                         \
        _Pragma("unroll")                                                      \
        for (int mi = 0; mi < 2; ++mi)                                         \
            afr[mi] = *reinterpret_cast<const short8*>(                        \
                &Ab[p][(32 * w + 16 * mi + (l & 15)) * APAD + (l >> 4) * 8]);  \
        _Pragma("unroll")                                                      \
        for (int mi = 0; mi < 2; ++mi)                                         \
            _Pragma("unroll")                                                  \
            for (int ni = 0; ni < 4; ++ni)                                     \
                acc[mi][ni] = __builtin_amdgcn_mfma_f32_16x16x32_bf16(         \
                    afr[mi], afr[ni & 1], acc[mi][ni], 0, 0, 0);               \
    }

    for (int rep = 0; rep < NABL; ++rep) {
        #pragma unroll
        for (int i = 0; i < 4; ++i) rA[i] = xp[i * 8 * D4v];
        #pragma unroll
        for (int i = 0; i < 4; ++i) rB[i] = xp[i * 8 * D4v + 8];
        #pragma unroll
        for (int i = 0; i < 4; ++i) cvt_store8(d0[i], rA[i]);
        __syncthreads();
        for (int kk = 0; kk < NSTEPS; kk += 2) {
            if (kk + 2 < NSTEPS) {
                #pragma unroll
                for (int i = 0; i < 4; ++i) rA[i] = xp[i * 8 * D4v + (kk + 2) * 8];
            }
            COMPUTE_NB(0);
            #pragma unroll
            for (int i = 0; i < 4; ++i) cvt_store8(d1[i], rB[i]);
            __syncthreads();
            if (kk + 3 < NSTEPS) {
                #pragma unroll
                for (int i = 0; i < 4; ++i) rB[i] = xp[i * 8 * D4v + (kk + 3) * 8];
            }
            COMPUTE_NB(1);
            if (kk + 2 < NSTEPS) {
                #pragma unroll
                for (int i = 0; i < 4; ++i) cvt_store8(d0[i], rA[i]);
                __syncthreads();
            }
        }
    }
#undef COMPUTE_NB
    float s = 0.f;
    #pragma unroll
    for (int mi = 0; mi < 2; ++mi)
        #pragma unroll
        for (int ni = 0; ni < 4; ++ni)
            s += acc[mi][ni][0] + acc[mi][ni][1] + acc[mi][ni][2] + acc[mi][ni][3];
    ws[(size_t)blockIdx.x * NTH + t] = s;
}

extern "C" void kernel_launch(void* const* d_in, const int* in_sizes, int n_in,
                              void* d_out, int out_size, void* d_ws, size_t ws_size,
                              hipStream_t stream) {
    const float* x     = (const float*)d_in[0];
    const float* W     = (const float*)d_in[1];
    const float* bias  = (const float*)d_in[2];
    const int*   query = (const int*)d_in[4];
    float* out = (float*)d_out;

    unsigned short* Wt = (unsigned short*)d_ws;             // 96 KiB
    float* ws1 = (float*)((char*)d_ws + (1 << 20));
    float* ws2 = (float*)((char*)d_ws + (3 << 20));

    const int nrows = in_sizes[0] / DIM;                    // 262144
    const int nblk  = nrows / MTB;                          // 1024

    wconv_kernel<<<(NCP * DIM + 255) / 256, 256, 0, stream>>>(W, Wt);
    bag_attn_blds<<<nblk, NTH, 0, stream>>>(x, Wt, bias, query, out);

    abl_stage<<<nblk, NTH, 0, stream>>>(x, ws1);
    abl_noB  <<<nblk, NTH, 0, stream>>>(x, ws2);
}

// Round 16
// 189.020 us; speedup vs baseline: 14.8313x; 5.0064x over previous
//
#include <hip/hip_runtime.h>
#include <hip/hip_bf16.h>

// N=262144 sentences (uniform 16/bag, contiguous), D=768, C=53
// Y = X * W^T via bf16 MFMA (R10 structure, best=192us). R16 change:
// MTB 256->128, NTH 512->256. Same per-wave work/staging/epilogue; LDS
// 40KB->20KB so blocks/CU rises ~2-3 -> ~5-6 independent barrier groups,
// decorrelating phase stalls (R15 ablation: kernel is latency-bound with
// nothing >15% busy; occupancy was the only abnormal counter).
#define DIM    768
#define NC     53
#define NCP    64
#define MTB    128     // rows per block (8 bags)
#define NTH    256     // 4 waves
#define KSTEP  32
#define NSTEPS 24      // 768/32
#define APAD   40      // LDS row stride in bf16 (80 B rows -> 2-way banks, free)
#define D4v    192

typedef __attribute__((ext_vector_type(8))) short short8;
typedef __attribute__((ext_vector_type(4))) float f32x4;

static __device__ inline unsigned short f2bf(float f) {
    unsigned u = __float_as_uint(f);
    u += 0x7fff + ((u >> 16) & 1);           // RNE
    return (unsigned short)(u >> 16);
}

// ---- kernel 1: W fp32 [53][768] -> bf16 [64][768] in d_ws ----
__global__ void wconv_kernel(const float* __restrict__ W, unsigned short* __restrict__ Wt) {
    const int idx = blockIdx.x * 256 + threadIdx.x;
    if (idx >= NCP * DIM) return;
    const int c = idx / DIM, k = idx - c * DIM;
    Wt[idx] = f2bf((c < NC) ? W[c * DIM + k] : 0.f);
}

// 4 fp32 -> 4 bf16 (8 B) via packed cvt
static __device__ inline void cvt_store8(unsigned short* dst, const float4 v) {
    union { __hip_bfloat162 h[2]; uint2 u; } z;
    z.h[0] = __float22bfloat162_rn(make_float2(v.x, v.y));
    z.h[1] = __float22bfloat162_rn(make_float2(v.z, v.w));
    *reinterpret_cast<uint2*>(dst) = z.u;
}

__global__ __launch_bounds__(NTH) void bag_attn_mfma5(
    const float* __restrict__ x,              // [N][768] fp32
    const unsigned short* __restrict__ Wt,    // [64][768] bf16 (d_ws)
    const float* __restrict__ bias,           // [53]
    const int*   __restrict__ query,          // [N]
    float*       __restrict__ out)            // [B][53]
{
    __shared__ __align__(16) unsigned short Ab[2][MTB * APAD];  // 20 KiB
    __shared__ float att_sm[8][16];
    __shared__ int   qbuf[MTB];

    const int t   = threadIdx.x;
    const int w   = t >> 6;        // wave 0..3 -> rows 32w..32w+31 (bags 2w,2w+1)
    const int l   = t & 63;
    const int blk = blockIdx.x;
    const int row_g = blk * MTB;

    if (t < MTB) qbuf[t] = query[row_g + t];

    // staging map (cache-line-complete): load i, lane l ->
    //   row = 32w + 8i + (l>>3), 16B at byte (l&7)*16 of the row's 128B k-chunk
    const float4* xp = reinterpret_cast<const float4*>(x)
                     + (size_t)(row_g + 32 * w + (l >> 3)) * D4v + (l & 7);
    unsigned short* d0[4];
    unsigned short* d1[4];
    #pragma unroll
    for (int i = 0; i < 4; ++i) {
        const int off = (32 * w + 8 * i + (l >> 3)) * APAD + (l & 7) * 4;
        d0[i] = &Ab[0][off];
        d1[i] = &Ab[1][off];
    }

    f32x4 acc[2][4];
    #pragma unroll
    for (int mi = 0; mi < 2; ++mi)
        #pragma unroll
        for (int ni = 0; ni < 4; ++ni)
            acc[mi][ni] = (f32x4){0.f, 0.f, 0.f, 0.f};

    float4 rA[4], rB[4];
    #pragma unroll
    for (int i = 0; i < 4; ++i) rA[i] = xp[i * 8 * D4v + 0 * 8];  // tile 0
    #pragma unroll
    for (int i = 0; i < 4; ++i) rB[i] = xp[i * 8 * D4v + 1 * 8];  // tile 1
    #pragma unroll
    for (int i = 0; i < 4; ++i) cvt_store8(d0[i], rA[i]);
    __syncthreads();

#define COMPUTE(p, kk)                                                         \
    {                                                                          \
        short8 bfr[4];                                                         \
        _Pragma("unroll")                                                      \
        for (int ni = 0; ni < 4; ++ni)                                         \
            bfr[ni] = *reinterpret_cast<const short8*>(                        \
                Wt + ((16 * ni + (l & 15)) * DIM + (kk) * KSTEP + (l >> 4) * 8)); \
        short8 afr[2];                                                         \
        _Pragma("unroll")                                                      \
        for (int mi = 0; mi < 2; ++mi)                                         \
            afr[mi] = *reinterpret_cast<const short8*>(                        \
                &Ab[p][(32 * w + 16 * mi + (l & 15)) * APAD + (l >> 4) * 8]);  \
        _Pragma("unroll")                                                      \
        for (int mi = 0; mi < 2; ++mi)                                         \
            _Pragma("unroll")                                                  \
            for (int ni = 0; ni < 4; ++ni)                                     \
                acc[mi][ni] = __builtin_amdgcn_mfma_f32_16x16x32_bf16(         \
                    afr[mi], bfr[ni], acc[mi][ni], 0, 0, 0);                   \
    }

    for (int kk = 0; kk < NSTEPS; kk += 2) {
        // even phase: compute buf0 = tile kk; stage tile kk+1 -> buf1
        if (kk + 2 < NSTEPS) {
            #pragma unroll
            for (int i = 0; i < 4; ++i)
                rA[i] = xp[i * 8 * D4v + (kk + 2) * 8];
        }
        COMPUTE(0, kk);
        #pragma unroll
        for (int i = 0; i < 4; ++i) cvt_store8(d1[i], rB[i]);
        __syncthreads();
        // odd phase: compute buf1 = tile kk+1; stage tile kk+2 -> buf0
        if (kk + 3 < NSTEPS) {
            #pragma unroll
            for (int i = 0; i < 4; ++i)
                rB[i] = xp[i * 8 * D4v + (kk + 3) * 8];
        }
        COMPUTE(1, kk + 1);
        if (kk + 2 < NSTEPS) {
            #pragma unroll
            for (int i = 0; i < 4; ++i) cvt_store8(d0[i], rA[i]);
            __syncthreads();
        }
    }
#undef COMPUTE

    // ---- epilogue: att extraction (D-layout: col=lane&15, row=(l>>4)*4+reg) ----
    #pragma unroll
    for (int mi = 0; mi < 2; ++mi) {
        #pragma unroll
        for (int r = 0; r < 4; ++r) {
            const int s_loc = ((l >> 4) << 2) + r;
            const int q = qbuf[32 * w + 16 * mi + s_loc];
            if ((q & 15) == (l & 15)) {       // one lane per row matches
                float v = acc[mi][0][r];
                if ((q >> 4) == 1) v = acc[mi][1][r];
                if ((q >> 4) == 2) v = acc[mi][2][r];
                if ((q >> 4) == 3) v = acc[mi][3][r];
                att_sm[2 * w + mi][s_loc] = v;
            }
        }
    }
    // att_sm rows 2w,2w+1 written+read by wave w only

    #pragma unroll
    for (int mi = 0; mi < 2; ++mi) {
        const int bag = 2 * w + mi;
        const float4* a4 = reinterpret_cast<const float4*>(&att_sm[bag][0]);
        const float4 A0 = a4[0], A1 = a4[1], A2 = a4[2], A3 = a4[3];
        float mx = fmaxf(fmaxf(fmaxf(A0.x, A0.y), fmaxf(A0.z, A0.w)),
                  fmaxf(fmaxf(fmaxf(A1.x, A1.y), fmaxf(A1.z, A1.w)),
                  fmaxf(fmaxf(fmaxf(A2.x, A2.y), fmaxf(A2.z, A2.w)),
                        fmaxf(fmaxf(A3.x, A3.y), fmaxf(A3.z, A3.w)))));
        float zz = __expf(A0.x-mx)+__expf(A0.y-mx)+__expf(A0.z-mx)+__expf(A0.w-mx)
                 + __expf(A1.x-mx)+__expf(A1.y-mx)+__expf(A1.z-mx)+__expf(A1.w-mx)
                 + __expf(A2.x-mx)+__expf(A2.y-mx)+__expf(A2.z-mx)+__expf(A2.w-mx)
                 + __expf(A3.x-mx)+__expf(A3.y-mx)+__expf(A3.z-mx)+__expf(A3.w-mx);
        const float inv = 1.f / zz;
        const int grp = l >> 4;
        float4 As = A0;
        if (grp == 1) As = A1;
        if (grp == 2) As = A2;
        if (grp == 3) As = A3;
        const float w0 = __expf(As.x - mx) * inv;
        const float w1 = __expf(As.y - mx) * inv;
        const float w2 = __expf(As.z - mx) * inv;
        const float w3 = __expf(As.w - mx) * inv;
        #pragma unroll
        for (int ni = 0; ni < 4; ++ni) {
            float p = w0 * acc[mi][ni][0] + w1 * acc[mi][ni][1]
                    + w2 * acc[mi][ni][2] + w3 * acc[mi][ni][3];
            p += __shfl_xor(p, 16, 64);       // sum the 4 row-groups
            p += __shfl_xor(p, 32, 64);
            if (l < 16) {
                const int c = 16 * ni + l;
                if (c < NC)
                    out[(size_t)(blk * 8 + bag) * NC + c] = p + bias[c];
            }
        }
    }
}

extern "C" void kernel_launch(void* const* d_in, const int* in_sizes, int n_in,
                              void* d_out, int out_size, void* d_ws, size_t ws_size,
                              hipStream_t stream) {
    const float* x     = (const float*)d_in[0];   // [N][768]
    const float* W     = (const float*)d_in[1];   // [53][768]
    const float* bias  = (const float*)d_in[2];   // [53]
    const int*   query = (const int*)d_in[4];     // [N]
    float* out = (float*)d_out;                   // [B][53]

    unsigned short* Wt = (unsigned short*)d_ws;   // 64*768*2 = 96 KiB

    const int nrows = in_sizes[0] / DIM;          // 262144
    const int nblk  = nrows / MTB;                // 2048

    wconv_kernel<<<(NCP * DIM + 255) / 256, 256, 0, stream>>>(W, Wt);
    bag_attn_mfma5<<<nblk, NTH, 0, stream>>>(x, Wt, bias, query, out);
}